// Round 14
// baseline (94.505 us; speedup 1.0000x reference)
//
#include <hip/hip_runtime.h>

#define NQ 4
#define DIM 16
#define E 2   // elements per thread; H in SGPRs so no VGPR explosion (cf. R2/R12)

// Round 14: prep unchanged (verified R12/R13). Main: E=2 + tensor-chain
// contraction of o_q = u^T H_q v with u=(1,c0,s0)x(1,c1,s1), v=(1,c2,s2)x(1,c3,s3):
//   contract x3 -> x2 -> x1 -> x0, intermediates consumed immediately.
// H loads are wave-uniform compile-time-indexed -> s_load (scalar pipe),
// shared by both elements; two independent FMA chains cover SMEM waits.

typedef __attribute__((ext_vector_type(4))) float fv4;

constexpr int PA[10] = {0,0,0,0,1,1,1,2,2,3};
constexpr int PC[10] = {0,1,2,3,1,2,3,2,3,3};

__device__ constexpr float TC[10][9] = {
    {1, 1, 0,  1, 1, 0,  0, 0, 0},
    {0, 0, 1,  0, 0, 1,  0, 0, 0},
    {0, 0, 0,  0, 0, 0,  1, 1, 0},
    {0, 0, 0,  0, 0, 0,  0, 0, 1},
    {1,-1, 0,  1,-1, 0,  0, 0, 0},
    {0, 0, 0,  0, 0, 0,  0, 0, 1},
    {0, 0, 0,  0, 0, 0,  1,-1, 0},
    {1, 1, 0, -1,-1, 0,  0, 0, 0},
    {0, 0, 1,  0, 0,-1,  0, 0, 0},
    {1,-1, 0, -1, 1, 0,  0, 0, 0},
};

__global__ void __launch_bounds__(128)
qlayer_prep(const float* __restrict__ weights, fv4* __restrict__ hw)
{
    __shared__ __align__(16) float2 WT[DIM][DIM];
    __shared__ __align__(16) fv4 G4[100];

    if (threadIdx.x < DIM) {
        const int k = threadIdx.x;
        float sre[DIM], sim[DIM];
#pragma unroll
        for (int i = 0; i < DIM; ++i) { sre[i] = (i == k) ? 1.f : 0.f; sim[i] = 0.f; }
#pragma unroll
        for (int l = 0; l < 3; ++l) {
#pragma unroll
            for (int p = 0; p < NQ; ++p) {
                const float h = 0.5f * weights[l * NQ + p];
                const float s = __sinf(h), c = __cosf(h);
                const int mask = 1 << (NQ - 1 - p);
#pragma unroll
                for (int i = 0; i < DIM; ++i) {
                    if (i & mask) continue;
                    const int jj = i | mask;
                    const float ar = sre[i], ai = sim[i];
                    const float br = sre[jj], bi = sim[jj];
                    sre[i]  = c * ar + s * bi;
                    sim[i]  = c * ai - s * br;
                    sre[jj] = c * br + s * ai;
                    sim[jj] = c * bi - s * ar;
                }
            }
#pragma unroll
            for (int p = 0; p < NQ; ++p) {
                const int t = (p + 1) % NQ;
                float tr[DIM], ti[DIM];
#pragma unroll
                for (int i = 0; i < DIM; ++i) {
                    const int src = i ^ ((((i >> (NQ - 1 - p)) & 1)) << (NQ - 1 - t));
                    tr[i] = sre[src]; ti[i] = sim[src];
                }
#pragma unroll
                for (int i = 0; i < DIM; ++i) { sre[i] = tr[i]; sim[i] = ti[i]; }
            }
        }
#pragma unroll
        for (int i = 0; i < DIM; ++i) WT[k][i] = make_float2(sre[i], sim[i]);
    }
    __syncthreads();

    if (threadIdx.x < 100) {
        const int ac = threadIdx.x / 10, bd = threadIdx.x % 10;
        const int a = PA[ac], c = PC[ac], b = PA[bd], d = PC[bd];

        auto evalS = [&](int j, int k, float* sv) {
            float ar[4] = {0,0,0,0}, ai[4] = {0,0,0,0};
#pragma unroll
            for (int i = 0; i < DIM; ++i) {
                const float2 wj = WT[j][i], wk = WT[k][i];
                const float pr = wj.x * wk.x + wj.y * wk.y;
                const float pi = wj.x * wk.y - wj.y * wk.x;
#pragma unroll
                for (int q = 0; q < 4; ++q) {
                    const float s = ((i >> (3 - q)) & 1) ? -1.f : 1.f;
                    ar[q] += s * pr; ai[q] += s * pi;
                }
            }
            const int m = (__builtin_popcount(j) - __builtin_popcount(k)) & 3;
#pragma unroll
            for (int q = 0; q < 4; ++q)
                sv[q] = (m == 0) ? ar[q] : (m == 1) ? -ai[q] : (m == 2) ? -ar[q] : ai[q];
        };

        float s1[4], s2[4];
        evalS(4 * a + b, 4 * c + d, s1);
        evalS(4 * a + d, 4 * c + b, s2);
        const float u = ((a < c) ? 2.f : 1.f) * ((b < d) ? 1.f : 0.5f);
        fv4 gv; gv.x = u*(s1[0]+s2[0]); gv.y = u*(s1[1]+s2[1]);
        gv.z = u*(s1[2]+s2[2]); gv.w = u*(s1[3]+s2[3]);
        G4[ac * 10 + bd] = gv;
    }
    __syncthreads();

    if (threadIdx.x < 81) {
        const int i = threadIdx.x / 9, j = threadIdx.x % 9;
        fv4 acc = (fv4)(0.f);
#pragma unroll
        for (int ac = 0; ac < 10; ++ac) {
            const float ti = TC[ac][i];
            fv4 tj = (fv4)(0.f);
#pragma unroll
            for (int bd = 0; bd < 10; ++bd)
                tj += G4[ac * 10 + bd] * TC[bd][j];
            acc += tj * ti;
        }
        hw[i * 9 + j] = acc * 0.0625f;
    }
}

__global__ void __launch_bounds__(256)
qlayer_main(const float4* __restrict__ x,
            const fv4* __restrict__ hw,
            fv4* __restrict__ out, int B)
{
    const int base = blockIdx.x * (256 * E) + threadIdx.x;

    float cx[E][4], sx[E][4];
    bool ok[E];
#pragma unroll
    for (int e = 0; e < E; ++e) {
        const int gi = base + e * 256;
        ok[e] = gi < B;
        const float4 xv = ok[e] ? x[gi] : make_float4(0.f, 0.f, 0.f, 0.f);
        cx[e][0] = __cosf(xv.x); sx[e][0] = __sinf(xv.x);
        cx[e][1] = __cosf(xv.y); sx[e][1] = __sinf(xv.y);
        cx[e][2] = __cosf(xv.z); sx[e][2] = __sinf(xv.z);
        cx[e][3] = __cosf(xv.w); sx[e][3] = __sinf(xv.w);
    }

    fv4 T3[E][3];   // partial sums over i0 (x0-basis index)

#pragma unroll
    for (int i0 = 0; i0 < 3; ++i0) {
#pragma unroll
        for (int i1 = 0; i1 < 3; ++i1) {
            const int i = 3 * i0 + i1;
#pragma unroll
            for (int e = 0; e < E; ++e) {
                fv4 T2;
#pragma unroll
                for (int j2 = 0; j2 < 3; ++j2) {
                    const int b0 = i * 9 + j2 * 3;
                    // hw[...]: uniform, compile-time index -> s_load, merged x8/x16
                    fv4 t1 = hw[b0] + hw[b0 + 1] * cx[e][3] + hw[b0 + 2] * sx[e][3];
                    if (j2 == 0)      T2 = t1;
                    else if (j2 == 1) T2 += t1 * cx[e][2];
                    else              T2 += t1 * sx[e][2];
                }
                if (i1 == 0)      T3[e][i0] = T2;
                else if (i1 == 1) T3[e][i0] += T2 * cx[e][1];
                else              T3[e][i0] += T2 * sx[e][1];
            }
        }
    }

#pragma unroll
    for (int e = 0; e < E; ++e) {
        const fv4 o = T3[e][0] + T3[e][1] * cx[e][0] + T3[e][2] * sx[e][0];
        const int gi = base + e * 256;
        if (ok[e]) out[gi] = o;
    }
}

extern "C" void kernel_launch(void* const* d_in, const int* in_sizes, int n_in,
                              void* d_out, int out_size, void* d_ws, size_t ws_size,
                              hipStream_t stream)
{
    const float4* x = (const float4*)d_in[0];
    const float* w  = (const float*)d_in[1];
    fv4* out        = (fv4*)d_out;
    fv4* hw         = (fv4*)d_ws;     // 81 * 16 B = 1296 B
    const int B = in_sizes[0] / NQ;

    qlayer_prep<<<1, 128, 0, stream>>>(w, hw);

    const int block = 256;
    const int perBlock = block * E;
    const int grid = (B + perBlock - 1) / perBlock;
    qlayer_main<<<grid, block, 0, stream>>>(x, hw, out, B);
}

// Round 15
// 80.860 us; speedup vs baseline: 1.1687x; 1.1687x over previous
//
#include <hip/hip_runtime.h>

#define NQ 4
#define DIM 16

// Round 15: R13 (E=1, SGPR-path H, 9x9 double-angle table - best: 80.5us)
// + 3 independent accumulator chains (rows 0-2 / 3-5 / 6-8) so three
// SMEM-chunk->FMA dependency chains overlap per thread, + nontemporal store.
// E=1 is a hard empirical constraint: every E>1 variant (R2,R3,R7,R8,R9,
// R10,R12,R14) landed at 38-41us kernel-side vs 26-30us for E=1.

typedef __attribute__((ext_vector_type(4))) float fv4;

constexpr int PA[10] = {0,0,0,0,1,1,1,2,2,3};
constexpr int PC[10] = {0,1,2,3,1,2,3,2,3,3};

__device__ constexpr float TC[10][9] = {
    {1, 1, 0,  1, 1, 0,  0, 0, 0},
    {0, 0, 1,  0, 0, 1,  0, 0, 0},
    {0, 0, 0,  0, 0, 0,  1, 1, 0},
    {0, 0, 0,  0, 0, 0,  0, 0, 1},
    {1,-1, 0,  1,-1, 0,  0, 0, 0},
    {0, 0, 0,  0, 0, 0,  0, 0, 1},
    {0, 0, 0,  0, 0, 0,  1,-1, 0},
    {1, 1, 0, -1,-1, 0,  0, 0, 0},
    {0, 0, 1,  0, 0,-1,  0, 0, 0},
    {1,-1, 0, -1, 1, 0,  0, 0, 0},
};

__global__ void __launch_bounds__(128)
qlayer_prep(const float* __restrict__ weights, fv4* __restrict__ hw)
{
    __shared__ __align__(16) float2 WT[DIM][DIM];
    __shared__ __align__(16) fv4 G4[100];

    if (threadIdx.x < DIM) {
        const int k = threadIdx.x;
        float sre[DIM], sim[DIM];
#pragma unroll
        for (int i = 0; i < DIM; ++i) { sre[i] = (i == k) ? 1.f : 0.f; sim[i] = 0.f; }
#pragma unroll
        for (int l = 0; l < 3; ++l) {
#pragma unroll
            for (int p = 0; p < NQ; ++p) {
                const float h = 0.5f * weights[l * NQ + p];
                const float s = __sinf(h), c = __cosf(h);
                const int mask = 1 << (NQ - 1 - p);
#pragma unroll
                for (int i = 0; i < DIM; ++i) {
                    if (i & mask) continue;
                    const int jj = i | mask;
                    const float ar = sre[i], ai = sim[i];
                    const float br = sre[jj], bi = sim[jj];
                    sre[i]  = c * ar + s * bi;
                    sim[i]  = c * ai - s * br;
                    sre[jj] = c * br + s * ai;
                    sim[jj] = c * bi - s * ar;
                }
            }
#pragma unroll
            for (int p = 0; p < NQ; ++p) {
                const int t = (p + 1) % NQ;
                float tr[DIM], ti[DIM];
#pragma unroll
                for (int i = 0; i < DIM; ++i) {
                    const int src = i ^ ((((i >> (NQ - 1 - p)) & 1)) << (NQ - 1 - t));
                    tr[i] = sre[src]; ti[i] = sim[src];
                }
#pragma unroll
                for (int i = 0; i < DIM; ++i) { sre[i] = tr[i]; sim[i] = ti[i]; }
            }
        }
#pragma unroll
        for (int i = 0; i < DIM; ++i) WT[k][i] = make_float2(sre[i], sim[i]);
    }
    __syncthreads();

    if (threadIdx.x < 100) {
        const int ac = threadIdx.x / 10, bd = threadIdx.x % 10;
        const int a = PA[ac], c = PC[ac], b = PA[bd], d = PC[bd];

        auto evalS = [&](int j, int k, float* sv) {
            float ar[4] = {0,0,0,0}, ai[4] = {0,0,0,0};
#pragma unroll
            for (int i = 0; i < DIM; ++i) {
                const float2 wj = WT[j][i], wk = WT[k][i];
                const float pr = wj.x * wk.x + wj.y * wk.y;
                const float pi = wj.x * wk.y - wj.y * wk.x;
#pragma unroll
                for (int q = 0; q < 4; ++q) {
                    const float s = ((i >> (3 - q)) & 1) ? -1.f : 1.f;
                    ar[q] += s * pr; ai[q] += s * pi;
                }
            }
            const int m = (__builtin_popcount(j) - __builtin_popcount(k)) & 3;
#pragma unroll
            for (int q = 0; q < 4; ++q)
                sv[q] = (m == 0) ? ar[q] : (m == 1) ? -ai[q] : (m == 2) ? -ar[q] : ai[q];
        };

        float s1[4], s2[4];
        evalS(4 * a + b, 4 * c + d, s1);
        evalS(4 * a + d, 4 * c + b, s2);
        const float u = ((a < c) ? 2.f : 1.f) * ((b < d) ? 1.f : 0.5f);
        fv4 gv; gv.x = u*(s1[0]+s2[0]); gv.y = u*(s1[1]+s2[1]);
        gv.z = u*(s1[2]+s2[2]); gv.w = u*(s1[3]+s2[3]);
        G4[ac * 10 + bd] = gv;
    }
    __syncthreads();

    if (threadIdx.x < 81) {
        const int i = threadIdx.x / 9, j = threadIdx.x % 9;
        fv4 acc = (fv4)(0.f);
#pragma unroll
        for (int ac = 0; ac < 10; ++ac) {
            const float ti = TC[ac][i];
            fv4 tj = (fv4)(0.f);
#pragma unroll
            for (int bd = 0; bd < 10; ++bd)
                tj += G4[ac * 10 + bd] * TC[bd][j];
            acc += tj * ti;
        }
        hw[i * 9 + j] = acc * 0.0625f;
    }
}

__global__ void __launch_bounds__(256)
qlayer_main(const float4* __restrict__ x,
            const fv4* __restrict__ hw,
            fv4* __restrict__ out, int B)
{
    const int gi = blockIdx.x * 256 + threadIdx.x;
    if (gi >= B) return;

    const float4 xv = x[gi];
    const float cx0 = __cosf(xv.x), sx0 = __sinf(xv.x);
    const float cx1 = __cosf(xv.y), sx1 = __sinf(xv.y);
    const float cx2 = __cosf(xv.z), sx2 = __sinf(xv.z);
    const float cx3 = __cosf(xv.w), sx3 = __sinf(xv.w);

    float u[8], v[8];
    u[0] = cx1;       u[1] = sx1;       u[2] = cx0;
    u[3] = cx0 * cx1; u[4] = cx0 * sx1;
    u[5] = sx0;       u[6] = sx0 * cx1; u[7] = sx0 * sx1;
    v[0] = cx3;       v[1] = sx3;       v[2] = cx2;
    v[3] = cx2 * cx3; v[4] = cx2 * sx3;
    v[5] = sx2;       v[6] = sx2 * cx3; v[7] = sx2 * sx3;

    // Three independent accumulator chains (i = 0-2, 3-5, 6-8): three
    // concurrent SMEM-chunk -> FMA dependency chains per thread.
    fv4 oA = (fv4)(0.f), oB = (fv4)(0.f), oC = (fv4)(0.f);

#pragma unroll
    for (int k = 0; k < 3; ++k) {
        const int iA = k, iB = 3 + k, iC = 6 + k;

        fv4 tA = hw[iA * 9];
        fv4 tB = hw[iB * 9];
        fv4 tC = hw[iC * 9];
#pragma unroll
        for (int j = 1; j < 9; ++j) {
            const float vj = v[j - 1];
            tA += hw[iA * 9 + j] * vj;
            tB += hw[iB * 9 + j] * vj;
            tC += hw[iC * 9 + j] * vj;
        }
        if (k == 0) { oA = tA; }            // u_0 = 1
        else        { oA += tA * u[k - 1]; }
        oB += tB * u[2 + k];                // rows 3..5 pair with u[2..4]
        oC += tC * u[5 + k];                // rows 6..8 pair with u[5..7]
    }

    const fv4 o = (oA + oB) + oC;
    __builtin_nontemporal_store(o, &out[gi]);
}

extern "C" void kernel_launch(void* const* d_in, const int* in_sizes, int n_in,
                              void* d_out, int out_size, void* d_ws, size_t ws_size,
                              hipStream_t stream)
{
    const float4* x = (const float4*)d_in[0];
    const float* w  = (const float*)d_in[1];
    fv4* out        = (fv4*)d_out;
    fv4* hw         = (fv4*)d_ws;     // 81 * 16 B = 1296 B
    const int B = in_sizes[0] / NQ;

    qlayer_prep<<<1, 128, 0, stream>>>(w, hw);

    const int block = 256;
    const int grid = (B + block - 1) / block;    // E=1
    qlayer_main<<<grid, block, 0, stream>>>(x, hw, out, B);
}

// Round 17
// 80.479 us; speedup vs baseline: 1.1743x; 1.0047x over previous
//
#include <hip/hip_runtime.h>

#define NQ 4
#define DIM 16
#define BLK 512   // 8 waves/block: halves block count vs 256, better packing

// Round 17 = Round 16 with the compile fix: nontemporal load must go through
// an ext_vector_type pointer (fv4), not HIP_vector_type (float4).
// prep: weights -> W -> G -> H=(1/16)TGT^T (9x9 fv4, d_ws), verified R12-R15.
// main: E=1 (hard empirical constraint: every E>1 variant cost +12-14us),
//  o_q = u^T H_q v, u/v = full-angle {1,cos,sin} tensor bases, H via
//  wave-uniform compile-time-indexed loads (s_load path).

typedef __attribute__((ext_vector_type(4))) float fv4;

constexpr int PA[10] = {0,0,0,0,1,1,1,2,2,3};
constexpr int PC[10] = {0,1,2,3,1,2,3,2,3,3};

__device__ constexpr float TC[10][9] = {
    {1, 1, 0,  1, 1, 0,  0, 0, 0},
    {0, 0, 1,  0, 0, 1,  0, 0, 0},
    {0, 0, 0,  0, 0, 0,  1, 1, 0},
    {0, 0, 0,  0, 0, 0,  0, 0, 1},
    {1,-1, 0,  1,-1, 0,  0, 0, 0},
    {0, 0, 0,  0, 0, 0,  0, 0, 1},
    {0, 0, 0,  0, 0, 0,  1,-1, 0},
    {1, 1, 0, -1,-1, 0,  0, 0, 0},
    {0, 0, 1,  0, 0,-1,  0, 0, 0},
    {1,-1, 0, -1, 1, 0,  0, 0, 0},
};

__global__ void __launch_bounds__(128)
qlayer_prep(const float* __restrict__ weights, fv4* __restrict__ hw)
{
    __shared__ __align__(16) float2 WT[DIM][DIM];
    __shared__ __align__(16) fv4 G4[100];

    if (threadIdx.x < DIM) {
        const int k = threadIdx.x;
        float sre[DIM], sim[DIM];
#pragma unroll
        for (int i = 0; i < DIM; ++i) { sre[i] = (i == k) ? 1.f : 0.f; sim[i] = 0.f; }
#pragma unroll
        for (int l = 0; l < 3; ++l) {
#pragma unroll
            for (int p = 0; p < NQ; ++p) {
                const float h = 0.5f * weights[l * NQ + p];
                const float s = __sinf(h), c = __cosf(h);
                const int mask = 1 << (NQ - 1 - p);
#pragma unroll
                for (int i = 0; i < DIM; ++i) {
                    if (i & mask) continue;
                    const int jj = i | mask;
                    const float ar = sre[i], ai = sim[i];
                    const float br = sre[jj], bi = sim[jj];
                    sre[i]  = c * ar + s * bi;
                    sim[i]  = c * ai - s * br;
                    sre[jj] = c * br + s * ai;
                    sim[jj] = c * bi - s * ar;
                }
            }
#pragma unroll
            for (int p = 0; p < NQ; ++p) {
                const int t = (p + 1) % NQ;
                float tr[DIM], ti[DIM];
#pragma unroll
                for (int i = 0; i < DIM; ++i) {
                    const int src = i ^ ((((i >> (NQ - 1 - p)) & 1)) << (NQ - 1 - t));
                    tr[i] = sre[src]; ti[i] = sim[src];
                }
#pragma unroll
                for (int i = 0; i < DIM; ++i) { sre[i] = tr[i]; sim[i] = ti[i]; }
            }
        }
#pragma unroll
        for (int i = 0; i < DIM; ++i) WT[k][i] = make_float2(sre[i], sim[i]);
    }
    __syncthreads();

    if (threadIdx.x < 100) {
        const int ac = threadIdx.x / 10, bd = threadIdx.x % 10;
        const int a = PA[ac], c = PC[ac], b = PA[bd], d = PC[bd];

        auto evalS = [&](int j, int k, float* sv) {
            float ar[4] = {0,0,0,0}, ai[4] = {0,0,0,0};
#pragma unroll
            for (int i = 0; i < DIM; ++i) {
                const float2 wj = WT[j][i], wk = WT[k][i];
                const float pr = wj.x * wk.x + wj.y * wk.y;
                const float pi = wj.x * wk.y - wj.y * wk.x;
#pragma unroll
                for (int q = 0; q < 4; ++q) {
                    const float s = ((i >> (3 - q)) & 1) ? -1.f : 1.f;
                    ar[q] += s * pr; ai[q] += s * pi;
                }
            }
            const int m = (__builtin_popcount(j) - __builtin_popcount(k)) & 3;
#pragma unroll
            for (int q = 0; q < 4; ++q)
                sv[q] = (m == 0) ? ar[q] : (m == 1) ? -ai[q] : (m == 2) ? -ar[q] : ai[q];
        };

        float s1[4], s2[4];
        evalS(4 * a + b, 4 * c + d, s1);
        evalS(4 * a + d, 4 * c + b, s2);
        const float u = ((a < c) ? 2.f : 1.f) * ((b < d) ? 1.f : 0.5f);
        fv4 gv; gv.x = u*(s1[0]+s2[0]); gv.y = u*(s1[1]+s2[1]);
        gv.z = u*(s1[2]+s2[2]); gv.w = u*(s1[3]+s2[3]);
        G4[ac * 10 + bd] = gv;
    }
    __syncthreads();

    if (threadIdx.x < 81) {
        const int i = threadIdx.x / 9, j = threadIdx.x % 9;
        fv4 acc = (fv4)(0.f);
#pragma unroll
        for (int ac = 0; ac < 10; ++ac) {
            const float ti = TC[ac][i];
            fv4 tj = (fv4)(0.f);
#pragma unroll
            for (int bd = 0; bd < 10; ++bd)
                tj += G4[ac * 10 + bd] * TC[bd][j];
            acc += tj * ti;
        }
        hw[i * 9 + j] = acc * 0.0625f;
    }
}

__global__ void __launch_bounds__(BLK)
qlayer_main(const fv4* __restrict__ x,
            const fv4* __restrict__ hw,
            fv4* __restrict__ out, int B)
{
    const int gi = blockIdx.x * BLK + threadIdx.x;
    if (gi >= B) return;

    const fv4 xv = __builtin_nontemporal_load(&x[gi]);   // pure streaming
    const float cx0 = __cosf(xv.x), sx0 = __sinf(xv.x);
    const float cx1 = __cosf(xv.y), sx1 = __sinf(xv.y);
    const float cx2 = __cosf(xv.z), sx2 = __sinf(xv.z);
    const float cx3 = __cosf(xv.w), sx3 = __sinf(xv.w);

    float u[8], v[8];
    u[0] = cx1;       u[1] = sx1;       u[2] = cx0;
    u[3] = cx0 * cx1; u[4] = cx0 * sx1;
    u[5] = sx0;       u[6] = sx0 * cx1; u[7] = sx0 * sx1;
    v[0] = cx3;       v[1] = sx3;       v[2] = cx2;
    v[3] = cx2 * cx3; v[4] = cx2 * sx3;
    v[5] = sx2;       v[6] = sx2 * cx3; v[7] = sx2 * sx3;

    fv4 o = (fv4)(0.f);
#pragma unroll
    for (int i = 0; i < 9; ++i) {
        // hw: uniform address, compile-time index -> s_load (scalar pipe)
        fv4 t = hw[i * 9];                       // j = 0 (v_0 = 1)
#pragma unroll
        for (int j = 1; j < 9; ++j)
            t += hw[i * 9 + j] * v[j - 1];
        o = (i == 0) ? t : o + t * u[i - 1];     // u_0 = 1
    }

    __builtin_nontemporal_store(o, &out[gi]);
}

extern "C" void kernel_launch(void* const* d_in, const int* in_sizes, int n_in,
                              void* d_out, int out_size, void* d_ws, size_t ws_size,
                              hipStream_t stream)
{
    const fv4* x    = (const fv4*)d_in[0];
    const float* w  = (const float*)d_in[1];
    fv4* out        = (fv4*)d_out;
    fv4* hw         = (fv4*)d_ws;     // 81 * 16 B = 1296 B
    const int B = in_sizes[0] / NQ;

    qlayer_prep<<<1, 128, 0, stream>>>(w, hw);

    const int grid = (B + BLK - 1) / BLK;    // E=1
    qlayer_main<<<grid, BLK, 0, stream>>>(x, hw, out, B);
}